// Round 9
// baseline (846.059 us; speedup 1.0000x reference)
//
#include <hip/hip_runtime.h>

#define TPB 256
#define NB1 256    // stripe blocks for edge passes
#define NBUCK 512  // coarse buckets (dst>>8); supports N <= 131072

using half4_t = __attribute__((ext_vector_type(4))) _Float16;
using half8_t = __attribute__((ext_vector_type(8))) _Float16;
using f32x4 = __attribute__((ext_vector_type(4))) float;

// ---------------- CSR build: atomic-free MSD counting sort ----------------

__global__ __launch_bounds__(256) void hist1_k(const int* __restrict__ ei,
                                               int* __restrict__ hist, int E, int stripe) {
  __shared__ int h[NBUCK];
  for (int i = threadIdx.x; i < NBUCK; i += 256) h[i] = 0;
  __syncthreads();
  int b0 = blockIdx.x * stripe;
  int b1 = min(b0 + stripe, E);
  for (int e = b0 + threadIdx.x; e < b1; e += 256) atomicAdd(&h[ei[E + e] >> 8], 1);
  __syncthreads();
  for (int i = threadIdx.x; i < NBUCK; i += 256) hist[i * NB1 + blockIdx.x] = h[i];
}

__global__ void scan1_k(const int* __restrict__ src, int* __restrict__ out,
                        int* __restrict__ chunk, int n) {
  __shared__ int sh[TPB];
  int i = blockIdx.x * TPB + threadIdx.x;
  int v = (i < n) ? src[i] : 0;
  sh[threadIdx.x] = v;
  __syncthreads();
  for (int off = 1; off < TPB; off <<= 1) {
    int t = (threadIdx.x >= off) ? sh[threadIdx.x - off] : 0;
    __syncthreads();
    sh[threadIdx.x] += t;
    __syncthreads();
  }
  if (i < n) out[i] = sh[threadIdx.x] - v;
  if (threadIdx.x == TPB - 1) chunk[blockIdx.x] = sh[TPB - 1];
}

__global__ void scan2_k(int* __restrict__ chunk, int nb) {
  __shared__ int sh[512];
  int v = (threadIdx.x < nb) ? chunk[threadIdx.x] : 0;
  sh[threadIdx.x] = v;
  __syncthreads();
  for (int off = 1; off < 512; off <<= 1) {
    int t = (threadIdx.x >= off) ? sh[threadIdx.x - off] : 0;
    __syncthreads();
    sh[threadIdx.x] += t;
    __syncthreads();
  }
  if (threadIdx.x < nb) chunk[threadIdx.x] = sh[threadIdx.x] - v;
}

__global__ void scan3_k(int* __restrict__ out, const int* __restrict__ chunk, int n) {
  int i = blockIdx.x * TPB + threadIdx.x;
  if (i < n) out[i] += chunk[blockIdx.x];
}

// pack: src (24 bits) | low8(dst) << 24
__global__ __launch_bounds__(256) void scatter1_k(const int* __restrict__ ei,
                                                  const int* __restrict__ base,
                                                  unsigned* __restrict__ ebuf, int E,
                                                  int stripe) {
  __shared__ int cur[NBUCK];
  for (int i = threadIdx.x; i < NBUCK; i += 256) cur[i] = base[i * NB1 + blockIdx.x];
  __syncthreads();
  int b0 = blockIdx.x * stripe;
  int b1 = min(b0 + stripe, E);
  for (int e = b0 + threadIdx.x; e < b1; e += 256) {
    int s = ei[e];
    int d = ei[E + e];
    int p = atomicAdd(&cur[d >> 8], 1);
    ebuf[p] = (unsigned)s | ((unsigned)(d & 255) << 24);
  }
}

__global__ __launch_bounds__(256) void build_k(const unsigned* __restrict__ ebuf,
                                               const int* __restrict__ base,
                                               int* __restrict__ row_start,
                                               int* __restrict__ deg,
                                               float* __restrict__ invd,
                                               int* __restrict__ csr, int N, int E) {
  __shared__ int h[256];
  __shared__ int excl[256];
  __shared__ int bse[2];
  int b = blockIdx.x;
  int t = threadIdx.x;
  if (t == 0) {
    bse[0] = base[b * NB1];
    bse[1] = (b + 1 < NBUCK) ? base[(b + 1) * NB1] : E;
  }
  h[t] = 0;
  __syncthreads();
  int bs = bse[0], be = bse[1];
  for (int e = bs + t; e < be; e += 256) atomicAdd(&h[ebuf[e] >> 24], 1);
  __syncthreads();
  int v = h[t];
  excl[t] = v;
  __syncthreads();
  for (int off = 1; off < 256; off <<= 1) {
    int tv = (t >= off) ? excl[t - off] : 0;
    __syncthreads();
    excl[t] += tv;
    __syncthreads();
  }
  int ex = excl[t] - v;
  int node = b * 256 + t;
  if (node < N) {
    row_start[node] = bs + ex;
    deg[node] = v;
    invd[node] = 1.0f / fmaxf((float)v, 1.0f);
  }
  h[t] = bs + ex;
  __syncthreads();
  for (int e = bs + t; e < be; e += 256) {
    unsigned p = ebuf[e];
    int pos = atomicAdd(&h[p >> 24], 1);
    csr[pos] = (int)(p & 0xFFFFFFu);
  }
}

// ---------------- prep: f2h(x) planar + weight converts + head pack ----------------
// Planar fp16 layout: [4 planes][N][32 features]; plane stride N*32 halfs.

__global__ void prep_k(const float* __restrict__ x, _Float16* __restrict__ xhp, int n4,
                       int N,
                       const float* __restrict__ w0, const float* __restrict__ w1,
                       const float* __restrict__ w2, const float* __restrict__ w3,
                       const float* __restrict__ w4, const float* __restrict__ w5,
                       _Float16* __restrict__ wh,
                       const float* __restrict__ Wal, const float* __restrict__ War,
                       const float* __restrict__ ba, const float* __restrict__ Wsl,
                       const float* __restrict__ Wsr, const float* __restrict__ bsx,
                       const float* __restrict__ Wel, const float* __restrict__ Wer,
                       const float* __restrict__ be, _Float16* __restrict__ Wcat,
                       float* __restrict__ bcat) {
  int t = blockIdx.x * TPB + threadIdx.x;
  if (t < n4) {
    float4 v = ((const float4*)x)[t];
    half4_t o;
    o.x = (_Float16)v.x; o.y = (_Float16)v.y; o.z = (_Float16)v.z; o.w = (_Float16)v.w;
    int node = t >> 5, w = t & 31;            // w-th float4 of the 128-feature row
    int plane = w >> 3, off = (w & 7) * 4;    // features w*4.. -> plane, offset
    *(half4_t*)&xhp[(size_t)plane * N * 32 + (size_t)node * 32 + off] = o;
  }
  if (t < 6 * 4096) {
    int which = t >> 12, i = t & 4095;
    const float* src = which == 0 ? w0 : which == 1 ? w1 : which == 2 ? w2
                     : which == 3 ? w3 : which == 4 ? w4 : w5;
    float4 v = ((const float4*)src)[i];
    half4_t o;
    o.x = (_Float16)v.x; o.y = (_Float16)v.y; o.z = (_Float16)v.z; o.w = (_Float16)v.w;
    ((half4_t*)wh)[(size_t)which * 4096 + i] = o;
  }
  if (t < 2048) {
    float v = 0.f;
    if (t < 384) v = Wal[t];
    else if (t < 640) v = Wsl[t - 384];
    else if (t < 1024) v = Wel[t - 640];
    else if (t < 1408) v = War[t - 1024];
    else if (t < 1664) v = Wsr[t - 1408];
    else v = Wer[t - 1664];
    Wcat[t] = (_Float16)v;
  }
  if (t < 16) {
    float b = 0.f;
    if (t >= 8 && t < 11) b = ba[t - 8];
    else if (t >= 11 && t < 13) b = bsx[t - 11];
    else if (t >= 13) b = be[t - 13];
    bcat[t] = b;
  }
}

// ---------------- 32-feature planar mean aggregation ----------------
// One pass gathers ONE 3.2 MB feature plane (fits the 4 MB per-XCD L2: all
// concurrent blocks touch the same plane -> L2-resident, LLC sees only the
// ~26 MB first-touch + csr). One wave per node; slot=lane>>2 picks one of 16
// edge slots, q=lane&3 covers features q*8..q*8+7 (16 B). One instruction
// gathers 16 rows (64 B each = 1 L2 line). Accumulate packed fp16
// (v_pk_add_f16, 4 ops/load); reduce across 16 slots via 4-level packed
// shfl_xor (16 shuffles/node-pass); convert to f32 only for the invd scale.

static __device__ inline half8_t h8_shfl_xor(half8_t v, int m) {
  union U { half8_t h; int i[4]; } u, r;
  u.h = v;
#pragma unroll
  for (int k = 0; k < 4; ++k) r.i[k] = __shfl_xor(u.i[k], m);
  return r.h;
}

__global__ __launch_bounds__(256) void agg32_k(const _Float16* __restrict__ hp,
                                               const int* __restrict__ csr,
                                               const int* __restrict__ row_start,
                                               const int* __restrict__ deg,
                                               const float* __restrict__ invd,
                                               _Float16* __restrict__ outp, int n) {
  int node = (blockIdx.x << 2) + (threadIdx.x >> 6);
  if (node >= n) return;
  int lane = threadIdx.x & 63;
  int slot = lane >> 2;  // edge slot 0..15
  int q = lane & 3;      // feature quarter (8 halfs)
  int s = row_start[node];
  int c = deg[node];
  const _Float16* base = hp + (q << 3);
  half8_t acc;
#pragma unroll
  for (int k = 0; k < 8; ++k) acc[k] = (_Float16)0;
  int j = 0;
  if (c >= 32) {
    int idA = csr[s + slot];
    int idB = csr[s + 16 + slot];
    while (true) {
      half8_t vA = *(const half8_t*)&base[(size_t)idA * 32];
      half8_t vB = *(const half8_t*)&base[(size_t)idB * 32];
      j += 32;
      bool more = (j + 32 <= c);
      if (more) {
        idA = csr[s + j + slot];
        idB = csr[s + j + 16 + slot];
      }
      acc += vA;
      acc += vB;
      if (!more) break;
    }
  }
  if (j < c) {  // masked tail: 0..31 edges, both loads issued together
    int cm1 = c - 1;
#pragma unroll
    for (int p = 0; p < 2; ++p) {
      int e = j + p * 16 + slot;
      _Float16 m = (e < c) ? (_Float16)1 : (_Float16)0;
      int id = csr[s + min(e, cm1)];
      half8_t v = *(const half8_t*)&base[(size_t)id * 32];
      half8_t mm;
#pragma unroll
      for (int k = 0; k < 8; ++k) mm[k] = m;
      acc += v * mm;
    }
  }
  // reduce across 16 slots (lane xor 4, 8, 16, 32), packed fp16
  acc += h8_shfl_xor(acc, 4);
  acc += h8_shfl_xor(acc, 8);
  acc += h8_shfl_xor(acc, 16);
  acc += h8_shfl_xor(acc, 32);
  if (slot == 0) {
    float w = invd[node];
    half8_t r;
#pragma unroll
    for (int k = 0; k < 8; ++k) r[k] = (_Float16)((float)acc[k] * w);
    *(half8_t*)&outp[(size_t)node * 32 + (q << 3)] = r;
  }
}

// ---------------- dense dual GEMM: planar A, weights in LDS (XOR-swizzled) ----------------
// outh = relu(Aagg@Wl^T + Ah@Wr^T + b), planar in/out. Block = 4 waves, 64 rows.
// A fragment kb (K-block kb*32..+31) is exactly plane kb of the planar layout.
// Weight pair (64 KB) staged once per block, kc ^= row&7 swizzle. C layout:
// col=lane&15, row=quad*4+reg. Stores scatter to planes (same element count).

__global__ __launch_bounds__(256) void gemm2_k(
    const _Float16* __restrict__ Aagg, const _Float16* __restrict__ Ah,
    const _Float16* __restrict__ Wh,  // [2][128][128]: Wl then Wr
    const float* __restrict__ bias, _Float16* __restrict__ outh, int n, int N) {
  __shared__ _Float16 Ws[32768];  // 64 KB
  int tid = threadIdx.x;
  int wave = tid >> 6;
  int lane = tid & 63;
  int g = lane >> 4;
  int l = lane & 15;
  int m0 = blockIdx.x * 64 + wave * 16;
  int arow = m0 + l;
  bool valid = arow < n;
  size_t pstride = (size_t)N * 32;

  // prefetch A fragments (plane kb, offset g*8)
  half8_t afA[4], afH[4];
  if (valid) {
#pragma unroll
    for (int kb = 0; kb < 4; ++kb)
      afA[kb] = *(const half8_t*)&Aagg[(size_t)kb * pstride + (size_t)arow * 32 + g * 8];
#pragma unroll
    for (int kb = 0; kb < 4; ++kb)
      afH[kb] = *(const half8_t*)&Ah[(size_t)kb * pstride + (size_t)arow * 32 + g * 8];
  } else {
#pragma unroll
    for (int kb = 0; kb < 4; ++kb) {
#pragma unroll
      for (int jj = 0; jj < 8; ++jj) { afA[kb][jj] = (_Float16)0; afH[kb][jj] = (_Float16)0; }
    }
  }

  // stage weights: 256 rows x 16 chunks of 16 B; chunk kc stored at kc^(row&7)
#pragma unroll
  for (int it = 0; it < 16; ++it) {
    int ci = tid + it * 256;
    int row = ci >> 4;
    int kc = ci & 15;
    float4 v = *(const float4*)&Wh[(size_t)row * 128 + kc * 8];
    *(float4*)&Ws[(size_t)row * 128 + ((kc ^ (row & 7)) * 8)] = v;
  }
  __syncthreads();

  f32x4 acc[8];
#pragma unroll
  for (int ct = 0; ct < 8; ++ct) acc[ct] = (f32x4){0.f, 0.f, 0.f, 0.f};

#pragma unroll
  for (int kb = 0; kb < 4; ++kb) {
#pragma unroll
    for (int ct = 0; ct < 8; ++ct) {
      int row = ct * 16 + l;  // Wl row (s=0)
      half8_t bf = *(const half8_t*)&Ws[(size_t)row * 128 + (((kb * 4 + g) ^ (l & 7)) * 8)];
      acc[ct] = __builtin_amdgcn_mfma_f32_16x16x32_f16(afA[kb], bf, acc[ct], 0, 0, 0);
    }
  }
#pragma unroll
  for (int kb = 0; kb < 4; ++kb) {
#pragma unroll
    for (int ct = 0; ct < 8; ++ct) {
      int row = 128 + ct * 16 + l;  // Wr row (s=1)
      half8_t bf = *(const half8_t*)&Ws[(size_t)row * 128 + (((kb * 4 + g) ^ (l & 7)) * 8)];
      acc[ct] = __builtin_amdgcn_mfma_f32_16x16x32_f16(afH[kb], bf, acc[ct], 0, 0, 0);
    }
  }

#pragma unroll
  for (int ct = 0; ct < 8; ++ct) {
    int col = ct * 16 + l;
    float bc = bias[col];
    size_t pbase = (size_t)(ct >> 1) * pstride + (size_t)((ct & 1) * 16 + l);
#pragma unroll
    for (int r = 0; r < 4; ++r) {
      int row = m0 + g * 4 + r;
      if (row < n) {
        float v = fmaxf(acc[ct][r] + bc, 0.f);
        outh[pbase + (size_t)row * 32] = (_Float16)v;
      }
    }
  }
}

// ---------------- head GEMM: [n,16] = h3 @ Wcat^T + bcat, split outputs ----------------
// h3 is planar. head_g[n][8] = gathered part (32 B rows), head_r[n][8] = root.

__global__ __launch_bounds__(256) void head_gemm_k(const _Float16* __restrict__ h,
                                                   const _Float16* __restrict__ Wcat,
                                                   const float* __restrict__ bcat,
                                                   float* __restrict__ head_g,
                                                   float* __restrict__ head_r, int n,
                                                   int N) {
  __shared__ _Float16 Ws[2048];  // 16 rows x 128, kc swizzled
  __shared__ float bs[16];
  int tid = threadIdx.x;
  {
    int row = tid >> 4, kc = tid & 15;
    float4 v = *(const float4*)&Wcat[(size_t)row * 128 + kc * 8];
    *(float4*)&Ws[(size_t)row * 128 + ((kc ^ (row & 7)) * 8)] = v;
    if (tid < 16) bs[tid] = bcat[tid];
  }
  __syncthreads();
  int wave = tid >> 6;
  int lane = tid & 63;
  int g = lane >> 4;
  int l = lane & 15;
  int m0 = blockIdx.x * 64 + wave * 16;
  int arow = m0 + l;
  bool valid = arow < n;
  size_t pstride = (size_t)N * 32;
  f32x4 acc = (f32x4){0.f, 0.f, 0.f, 0.f};
#pragma unroll
  for (int kb = 0; kb < 4; ++kb) {
    half8_t af;
    if (valid) {
      af = *(const half8_t*)&h[(size_t)kb * pstride + (size_t)arow * 32 + g * 8];
    } else {
#pragma unroll
      for (int jj = 0; jj < 8; ++jj) af[jj] = (_Float16)0;
    }
    half8_t bf = *(const half8_t*)&Ws[(size_t)l * 128 + (((kb * 4 + g) ^ (l & 7)) * 8)];
    acc = __builtin_amdgcn_mfma_f32_16x16x32_f16(af, bf, acc, 0, 0, 0);
  }
  float bc = bs[l];
#pragma unroll
  for (int r = 0; r < 4; ++r) {
    int row = m0 + g * 4 + r;
    if (row < n) {
      float v = acc[r] + bc;
      if (l < 8) head_g[(size_t)row * 8 + l] = v;
      else head_r[(size_t)row * 8 + (l - 8)] = v;
    }
  }
}

// ---------------- 8-dim aggregation + output write ----------------
// out layout: age [n,3] @0, sex [n,2] @3n, eth [n,3] @5n

__global__ void agg8_k(const float* __restrict__ head_g, const float* __restrict__ head_r,
                       const int* __restrict__ csr, const int* __restrict__ row_start,
                       const int* __restrict__ deg, const float* __restrict__ invd,
                       float* __restrict__ out, int n) {
  int node = (blockIdx.x << 2) + (threadIdx.x >> 6);
  if (node >= n) return;
  int lane = threadIdx.x & 63;
  int c2 = lane & 3;  // feature pair
  int g = lane >> 2;  // edge slot 0..15
  int s = row_start[node], cnt = deg[node];
  float ax = 0.f, ay = 0.f;
  int j = 0;
  for (; j + 32 <= cnt; j += 32) {
#pragma unroll
    for (int p = 0; p < 2; ++p) {
      int id = csr[s + j + 16 * p + g];
      float2 v = *(const float2*)&head_g[(size_t)id * 8 + 2 * c2];
      ax += v.x;
      ay += v.y;
    }
  }
  if (j < cnt) {
    int cm1 = cnt - 1;
#pragma unroll
    for (int p = 0; p < 2; ++p) {
      int e = j + 16 * p + g;
      float m = (e < cnt) ? 1.f : 0.f;
      int id = csr[s + min(e, cm1)];
      float2 v = *(const float2*)&head_g[(size_t)id * 8 + 2 * c2];
      ax = fmaf(m, v.x, ax);
      ay = fmaf(m, v.y, ay);
    }
  }
  ax += __shfl_xor(ax, 4);  ay += __shfl_xor(ay, 4);
  ax += __shfl_xor(ax, 8);  ay += __shfl_xor(ay, 8);
  ax += __shfl_xor(ax, 16); ay += __shfl_xor(ay, 16);
  ax += __shfl_xor(ax, 32); ay += __shfl_xor(ay, 32);
  if (g == 0) {
    float w = invd[node];
    float r0 = ax * w + head_r[(size_t)node * 8 + 2 * c2];
    float r1 = ay * w + head_r[(size_t)node * 8 + 2 * c2 + 1];
    float rr[2] = {r0, r1};
#pragma unroll
    for (int q = 0; q < 2; ++q) {
      int f = 2 * c2 + q;
      float r = rr[q];
      if (f < 3) out[(size_t)node * 3 + f] = r;
      else if (f < 5) out[(size_t)3 * n + (size_t)node * 2 + (f - 3)] = r;
      else out[(size_t)5 * n + (size_t)node * 3 + (f - 5)] = r;
    }
  }
}

// ---------------- launch ----------------

extern "C" void kernel_launch(void* const* d_in, const int* in_sizes, int n_in,
                              void* d_out, int out_size, void* d_ws, size_t ws_size,
                              hipStream_t stream) {
  const float* x = (const float*)d_in[0];
  const int* ei = (const int*)d_in[1];
  const float* W1l = (const float*)d_in[2];
  const float* W1r = (const float*)d_in[3];
  const float* b1 = (const float*)d_in[4];
  const float* W2l = (const float*)d_in[5];
  const float* W2r = (const float*)d_in[6];
  const float* b2 = (const float*)d_in[7];
  const float* W3l = (const float*)d_in[8];
  const float* W3r = (const float*)d_in[9];
  const float* b3 = (const float*)d_in[10];
  const float* Wal = (const float*)d_in[11];
  const float* War = (const float*)d_in[12];
  const float* ba = (const float*)d_in[13];
  const float* Wsl = (const float*)d_in[14];
  const float* Wsr = (const float*)d_in[15];
  const float* bsx = (const float*)d_in[16];
  const float* Wel = (const float*)d_in[17];
  const float* Wer = (const float*)d_in[18];
  const float* be = (const float*)d_in[19];

  int N = in_sizes[0] / 128;
  int E = in_sizes[1] / 2;
  int NBKT = (N + 255) >> 8;

  char* w = (char*)d_ws;
  auto alloc = [&](size_t b) {
    char* p = w;
    w += (b + 255) & ~(size_t)255;
    return p;
  };
  int* deg = (int*)alloc((size_t)N * 4);
  int* row_start = (int*)alloc((size_t)N * 4);
  float* invd = (float*)alloc((size_t)N * 4);
  int* hist = (int*)alloc((size_t)NBUCK * NB1 * 4);
  int* chunk = (int*)alloc(512 * 4);
  int* csr = (int*)alloc((size_t)E * 4);
  // xh (fp16 x planar, N*128*2 B) aliases ebuf (E*4 B): ebuf dead after build_k.
  size_t xh_bytes = (size_t)N * 128 * 2;
  size_t ebuf_bytes = (size_t)E * 4;
  char* region = (char*)alloc(xh_bytes > ebuf_bytes ? xh_bytes : ebuf_bytes);
  unsigned* ebuf = (unsigned*)region;
  _Float16* xh = (_Float16*)region;
  _Float16* aggh = (_Float16*)alloc((size_t)N * 128 * 2);
  _Float16* hA = (_Float16*)alloc((size_t)N * 128 * 2);
  _Float16* hB = (_Float16*)alloc((size_t)N * 128 * 2);
  _Float16* wh = (_Float16*)alloc((size_t)6 * 16384 * 2);
  _Float16* Wcat = (_Float16*)alloc(2048 * 2);
  float* bcat = (float*)alloc(16 * 4);
  float* head_g = (float*)alloc((size_t)N * 8 * 4);
  float* head_r = (float*)alloc((size_t)N * 8 * 4);

  int stripe = (((E + NB1 - 1) / NB1) + 255) & ~255;
  int nscan = NBUCK * NB1;
  int nbScan = (nscan + TPB - 1) / TPB;
  int nbNode = (N + 3) / 4;
  int nbM = (N + 63) / 64;
  int nbC = (N * 32 + TPB - 1) / TPB;
  size_t pstride = (size_t)N * 32;  // halfs per plane

  // CSR build — no global atomics
  hist1_k<<<NB1, 256, 0, stream>>>(ei, hist, E, stripe);
  scan1_k<<<nbScan, TPB, 0, stream>>>(hist, hist, chunk, nscan);
  scan2_k<<<1, 512, 0, stream>>>(chunk, nbScan);
  scan3_k<<<nbScan, TPB, 0, stream>>>(hist, chunk, nscan);
  scatter1_k<<<NB1, 256, 0, stream>>>(ei, hist, ebuf, E, stripe);
  build_k<<<NBKT, 256, 0, stream>>>(ebuf, hist, row_start, deg, invd, csr, N, E);

  // conversions + packing (xh aliases ebuf: after build_k)
  prep_k<<<nbC, TPB, 0, stream>>>(x, xh, N * 32, N, W1l, W1r, W2l, W2r, W3l, W3r, wh,
                                  Wal, War, ba, Wsl, Wsr, bsx, Wel, Wer, be, Wcat, bcat);

  // layer 1: x -> hA (4 planar agg passes, then dual GEMM)
  for (int p = 0; p < 4; ++p)
    agg32_k<<<nbNode, TPB, 0, stream>>>(xh + p * pstride, csr, row_start, deg, invd,
                                        aggh + p * pstride, N);
  gemm2_k<<<nbM, TPB, 0, stream>>>(aggh, xh, wh + 0 * 16384, b1, hA, N, N);
  // layer 2: hA -> hB
  for (int p = 0; p < 4; ++p)
    agg32_k<<<nbNode, TPB, 0, stream>>>(hA + p * pstride, csr, row_start, deg, invd,
                                        aggh + p * pstride, N);
  gemm2_k<<<nbM, TPB, 0, stream>>>(aggh, hA, wh + 2 * 16384, b2, hB, N, N);
  // layer 3: hB -> hA
  for (int p = 0; p < 4; ++p)
    agg32_k<<<nbNode, TPB, 0, stream>>>(hB + p * pstride, csr, row_start, deg, invd,
                                        aggh + p * pstride, N);
  gemm2_k<<<nbM, TPB, 0, stream>>>(aggh, hB, wh + 4 * 16384, b3, hA, N, N);
  // heads: transform to split 8+8 layout, then aggregate
  head_gemm_k<<<nbM, TPB, 0, stream>>>(hA, Wcat, bcat, head_g, head_r, N, N);
  agg8_k<<<nbNode, TPB, 0, stream>>>(head_g, head_r, csr, row_start, deg, invd,
                                     (float*)d_out, N);
}